// Round 7
// baseline (157.587 us; speedup 1.0000x reference)
//
#include <hip/hip_runtime.h>

// Problem constants: x [B=16, C=256, H=128, W=128] f32 (NCHW)
#define BB 16
#define CC 256
#define HH 128
#define WW 128
#define HWSZ (HH * WW)          // 16384
#define HW4 (HWSZ / 4)          // 4096 float4 per plane
#define BHW (BB * HWSZ)         // 262144
#define TOTAL (BB * CC * HWSZ)  // 67108864

typedef float f32x4 __attribute__((ext_vector_type(4)));

// Kernel 1: channel pool. Block = 4 waves; wave w reduces channel chunk w
// (64 ch) over 128 float4 spatial positions (2 per lane -> 2 KiB bursts).
// Grid = 65536/128 = 512 blocks (2/CU, 8 waves/CU).
__global__ __launch_bounds__(256) void pool_kernel(const float* __restrict__ x,
                                                   float* __restrict__ pmax,
                                                   float* __restrict__ pmean) {
    __shared__ float4 smax[4][128];
    __shared__ float4 ssum[4][128];
    int t     = threadIdx.x;
    int lane  = t & 63;
    int chunk = t >> 6;
    int p0    = blockIdx.x * 128 + lane;     // float4 index, pos1 = p0+64
    int b     = p0 >> 12;                    // same b for p0 and p0+64
    int hw4   = p0 & (HW4 - 1);
    const float4* xb = (const float4*)x + ((size_t)b << 20) + ((size_t)chunk << 18) + hw4;

    float4 v0 = xb[0], v1 = xb[64];
    float4 mA = v0, sA = v0, mB = v1, sB = v1;
    #pragma unroll 4
    for (int c = 1; c < 64; ++c) {
        float4 u0 = xb[(size_t)(c << 12)];
        float4 u1 = xb[(size_t)(c << 12) + 64];
        mA.x = fmaxf(mA.x, u0.x); sA.x += u0.x;
        mA.y = fmaxf(mA.y, u0.y); sA.y += u0.y;
        mA.z = fmaxf(mA.z, u0.z); sA.z += u0.z;
        mA.w = fmaxf(mA.w, u0.w); sA.w += u0.w;
        mB.x = fmaxf(mB.x, u1.x); sB.x += u1.x;
        mB.y = fmaxf(mB.y, u1.y); sB.y += u1.y;
        mB.z = fmaxf(mB.z, u1.z); sB.z += u1.z;
        mB.w = fmaxf(mB.w, u1.w); sB.w += u1.w;
    }
    smax[chunk][lane]      = mA;  ssum[chunk][lane]      = sA;
    smax[chunk][lane + 64] = mB;  ssum[chunk][lane + 64] = sB;
    __syncthreads();

    if (t < 128) {
        float4 m0 = smax[0][t], m1 = smax[1][t], m2 = smax[2][t], m3 = smax[3][t];
        float4 a0 = ssum[0][t], a1 = ssum[1][t], a2 = ssum[2][t], a3 = ssum[3][t];
        float4 m, a;
        m.x = fmaxf(fmaxf(m0.x, m1.x), fmaxf(m2.x, m3.x));
        m.y = fmaxf(fmaxf(m0.y, m1.y), fmaxf(m2.y, m3.y));
        m.z = fmaxf(fmaxf(m0.z, m1.z), fmaxf(m2.z, m3.z));
        m.w = fmaxf(fmaxf(m0.w, m1.w), fmaxf(m2.w, m3.w));
        const float inv = 1.0f / (float)CC;
        a.x = (a0.x + a1.x + a2.x + a3.x) * inv;
        a.y = (a0.y + a1.y + a2.y + a3.y) * inv;
        a.z = (a0.z + a1.z + a2.z + a3.z) * inv;
        a.w = (a0.w + a1.w + a2.w + a3.w) * inv;
        int gp = blockIdx.x * 128 + t;
        ((float4*)pmax)[gp]  = m;
        ((float4*)pmean)[gp] = a;
    }
}

// Kernel 2: 7x7 conv + bias + BN + sigmoid -> att (1 MiB, temporal: keep hot).
__global__ __launch_bounds__(256) void conv_kernel(const float* __restrict__ pmax,
                                                   const float* __restrict__ pmean,
                                                   const float* __restrict__ cw,
                                                   const float* __restrict__ cb,
                                                   const float* __restrict__ g,
                                                   const float* __restrict__ be,
                                                   const float* __restrict__ mu,
                                                   const float* __restrict__ var,
                                                   float* __restrict__ att) {
    __shared__ float w[98];
    __shared__ float sc[2];
    if (threadIdx.x < 98) w[threadIdx.x] = cw[threadIdx.x];
    if (threadIdx.x == 0) {
        float scale = g[0] * rsqrtf(var[0] + 1e-5f);
        sc[0] = scale;
        sc[1] = cb[0] * scale + be[0] - mu[0] * scale;
    }
    __syncthreads();

    int s  = blockIdx.x * 256 + threadIdx.x;
    int b  = s >> 14;
    int hw = s & (HWSZ - 1);
    int h  = hw >> 7;
    int ww = hw & 127;
    const float* pm = pmax  + (size_t)b * HWSZ;
    const float* pa = pmean + (size_t)b * HWSZ;

    float acc = 0.0f;
    #pragma unroll
    for (int kh = 0; kh < 7; ++kh) {
        int hh = h + kh - 3;
        if ((unsigned)hh < (unsigned)HH) {
            int rowoff = hh << 7;
            #pragma unroll
            for (int kw = 0; kw < 7; ++kw) {
                int wcol = ww + kw - 3;
                if ((unsigned)wcol < (unsigned)WW) {
                    int o = rowoff + wcol;
                    acc = fmaf(w[kh * 7 + kw],      pm[o], acc);
                    acc = fmaf(w[49 + kh * 7 + kw], pa[o], acc);
                }
            }
        }
    }
    float y = fmaf(acc, sc[0], sc[1]);
    att[s] = 1.0f / (1.0f + __expf(-y));
}

// Kernel 3: gate. Block = (b, group of 8 channels). Stage att[b] (64 KB) in
// LDS, then stream 8 full planes FULLY CONTIGUOUSLY: temporal x load, fma,
// NT out store. Grid = 16*32 = 512 blocks, 2 blocks/CU (LDS-limited).
__global__ __launch_bounds__(256) void gate_kernel(const float* __restrict__ x,
                                                   const float* __restrict__ att,
                                                   float* __restrict__ out) {
    __shared__ f32x4 satt[HW4];   // 64 KB: whole att map for batch b
    int t  = threadIdx.x;
    int cg = blockIdx.x & 31;     // channel group (8 ch)
    int b  = blockIdx.x >> 5;

    const f32x4* attv = (const f32x4*)att + ((size_t)b << 12);
    #pragma unroll
    for (int j = 0; j < 16; ++j)
        satt[j * 256 + t] = attv[j * 256 + t];
    __syncthreads();

    const f32x4* xv = (const f32x4*)x;
    f32x4*       ov = (f32x4*)out;
    // base float4 index of first plane: (b*256 + cg*8) * 4096
    size_t base = (((size_t)b << 8) + ((size_t)cg << 3)) << 12;
    #pragma unroll
    for (int p = 0; p < 8; ++p) {
        size_t pb = base + ((size_t)p << 12);
        #pragma unroll 8
        for (int k = 0; k < 16; ++k) {
            int o = k * 256 + t;
            f32x4 v = xv[pb + o];
            f32x4 a = satt[o];
            v.x *= a.x; v.y *= a.y; v.z *= a.z; v.w *= a.w;
            __builtin_nontemporal_store(v, ov + pb + o);
        }
    }
}

extern "C" void kernel_launch(void* const* d_in, const int* in_sizes, int n_in,
                              void* d_out, int out_size, void* d_ws, size_t ws_size,
                              hipStream_t stream) {
    const float* x   = (const float*)d_in[0];
    const float* cw  = (const float*)d_in[1];
    const float* cb  = (const float*)d_in[2];
    const float* g   = (const float*)d_in[3];
    const float* be  = (const float*)d_in[4];
    const float* mu  = (const float*)d_in[5];
    const float* var = (const float*)d_in[6];
    float* out = (float*)d_out;

    float* pmax  = (float*)d_ws;
    float* pmean = pmax + BHW;
    float* att   = pmean + BHW;

    pool_kernel<<<512, 256, 0, stream>>>(x, pmax, pmean);
    conv_kernel<<<BHW / 256, 256, 0, stream>>>(pmax, pmean, cw, cb, g, be, mu, var, att);
    gate_kernel<<<512, 256, 0, stream>>>(x, att, out);
}